// Round 4
// baseline (453.586 us; speedup 1.0000x reference)
//
#include <hip/hip_runtime.h>
#include <stdint.h>

// Ternary CNN, 7 layers. L0: fp64-exact conv+pool+sign (NCHW). L1-L2: sdot4
// kernels (NCHW in; L2 emits NHWC). L3-L6: implicit-GEMM int8 MFMA in NHWC
// with register double-buffered B-fragments (prefetch next 16-pixel fragment
// before issuing the current fragment's MFMAs -> partial vmcnt waits instead
// of a full drain per iteration). L4 uses MTILES=4 (all 64 couts per block)
// to double the MFMA:VMEM ratio.
//
// Workspace ping-pong:
//  A @ 0        : L0 out NCHW (64,4,127,s128) 4.2MB ; L2 out NHWC (64,123,123,16) 15.5MB ;
//                 L4 out NHWC (64,119,119,64) 58.0MB
//  B @ 58491136 : L1 out NCHW (64,8,125,s128) 8.2MB ; L3 out NHWC (64,121,121,32) 30.0MB ;
//                 L5 out NHWC (64,117,117,32) 28.1MB

#define DEVINL __device__ __forceinline__
typedef int i32x4 __attribute__((ext_vector_type(4)));

DEVINL uint32_t alignb(uint32_t hi, uint32_t lo, int k) {
#if __has_builtin(__builtin_amdgcn_alignbyte)
    return __builtin_amdgcn_alignbyte(hi, lo, (uint32_t)k);
#else
    return (uint32_t)(((((uint64_t)hi) << 32) | (uint64_t)lo) >> (8 * k));
#endif
}

DEVINL int dot4(uint32_t a, uint32_t b, int c) {
#if __has_builtin(__builtin_amdgcn_sdot4)
    return __builtin_amdgcn_sdot4((int)a, (int)b, c, false);
#else
    #pragma unroll
    for (int i = 0; i < 4; ++i)
        c += (int)(int8_t)(a >> (8 * i)) * (int)(int8_t)(b >> (8 * i));
    return c;
#endif
}

// ---------------- Layer 0: conv(raw fp32, sign(w)) -> maxpool2 -> sign -> int8 NCHW s128
__global__ __launch_bounds__(256) void conv0_pool_sign(
    const float* __restrict__ x, const float* __restrict__ w,
    int8_t* __restrict__ out)
{
    __shared__ float ws[108];
    const int t = threadIdx.x;
    if (t < 108) {
        float v = w[t];
        ws[t] = (v > 0.f) ? 1.f : ((v < 0.f) ? -1.f : 0.f);
    }
    __syncthreads();
    const int idx = blockIdx.x * 256 + t;   // 64*4*127*127 = 16129*256
    const int px = idx % 127;
    const int py = (idx / 127) % 127;
    const int co = (idx / (127 * 127)) % 4;
    const int n  = idx / (127 * 127 * 4);

    double a00 = 0.0, a01 = 0.0, a10 = 0.0, a11 = 0.0;
    const float* wsc = &ws[co * 27];
    for (int ci = 0; ci < 3; ++ci) {
        float patch[4][4];
        const float* xp = x + (((size_t)n * 3 + ci) * 256 + 2 * py) * 256 + 2 * px;
        #pragma unroll
        for (int r = 0; r < 4; ++r) {
            // 8B-aligned float2 loads (2*px is even); values (and accumulation
            // order below) identical to scalar loads.
            const float2* q = (const float2*)(xp + r * 256);
            float2 p01 = q[0], p23 = q[1];
            patch[r][0] = p01.x; patch[r][1] = p01.y;
            patch[r][2] = p23.x; patch[r][3] = p23.y;
        }
        #pragma unroll
        for (int ky = 0; ky < 3; ++ky)
            #pragma unroll
            for (int kx = 0; kx < 3; ++kx) {
                const double wv = (double)wsc[ci * 9 + ky * 3 + kx];
                a00 += (double)patch[ky][kx]         * wv;
                a01 += (double)patch[ky][kx + 1]     * wv;
                a10 += (double)patch[ky + 1][kx]     * wv;
                a11 += (double)patch[ky + 1][kx + 1] * wv;
            }
    }
    const double m = fmax(fmax(a00, a01), fmax(a10, a11));
    const size_t o = (((size_t)n * 4 + co) * 127 + py) * 128 + px;
    out[o] = (m > 0.0) ? (int8_t)1 : ((m < 0.0) ? (int8_t)(-1) : (int8_t)0);
}

// ---------------- L1/L2: ternary conv via sdot4 (NCHW in). OUT_NHWC: byte-store NHWC.
template <int CIN, int CO, bool OUT_NHWC>
__global__ __launch_bounds__(256) void conv_dot(
    const int8_t* __restrict__ in, const float* __restrict__ w,
    int8_t* __restrict__ outp, int cout, int W, int WS, int Wo, int WSo)
{
    __shared__ uint32_t pw[CIN * 3 * CO];
    const int t  = threadIdx.x;
    const int cg = blockIdx.x;
    const int n  = blockIdx.z;
    for (int i = t; i < CIN * 3 * CO; i += 256) {
        const int co = i % CO;
        const int r  = i / CO;
        const int ky = r % 3;
        const int ci = r / 3;
        const float* wp = w + (((size_t)(cg * CO + co) * CIN + ci) * 9 + ky * 3);
        uint32_t u = 0;
        #pragma unroll
        for (int k = 0; k < 3; ++k) {
            float v = wp[k];
            int s = (v > 0.f) ? 1 : ((v < 0.f) ? -1 : 0);
            u |= ((uint32_t)(uint8_t)(int8_t)s) << (8 * k);
        }
        pw[i] = u;
    }
    __syncthreads();

    const int tiles_x = (Wo + 63) >> 6;
    const int bx = blockIdx.y % tiles_x;
    const int by = blockIdx.y / tiles_x;
    const int px = bx * 64 + (t & 15) * 4;
    const int py = by * 32 + (t >> 4) * 2;
    if (px >= Wo || py >= Wo) return;

    const size_t ch = (size_t)W * WS;
    const int8_t* p0 = in + (size_t)n * CIN * ch + (size_t)py * WS + px;
    const int r3off = (py + 3 < W) ? 3 * WS : 0;

    int acc[CO][2][4];
    #pragma unroll
    for (int co = 0; co < CO; ++co)
        #pragma unroll
        for (int rr = 0; rr < 2; ++rr)
            #pragma unroll
            for (int j = 0; j < 4; ++j) acc[co][rr][j] = 0;

    #pragma unroll 2
    for (int ci = 0; ci < CIN; ++ci) {
        const int8_t* p = p0 + (size_t)ci * ch;
        uint32_t da[4], db[4];
        {
            const uint32_t* q0 = (const uint32_t*)p;
            const uint32_t* q1 = (const uint32_t*)(p + WS);
            const uint32_t* q2 = (const uint32_t*)(p + 2 * WS);
            const uint32_t* q3 = (const uint32_t*)(p + r3off);
            da[0] = q0[0]; db[0] = q0[1];
            da[1] = q1[0]; db[1] = q1[1];
            da[2] = q2[0]; db[2] = q2[1];
            da[3] = q3[0]; db[3] = q3[1];
        }
        uint32_t wv[3][CO];
        #pragma unroll
        for (int ky = 0; ky < 3; ++ky)
            #pragma unroll
            for (int co = 0; co < CO; ++co)
                wv[ky][co] = pw[(ci * 3 + ky) * CO + co];

        #pragma unroll
        for (int r = 0; r < 4; ++r) {
            uint32_t sw[4];
            sw[0] = da[r];
            sw[1] = alignb(db[r], da[r], 1);
            sw[2] = alignb(db[r], da[r], 2);
            sw[3] = alignb(db[r], da[r], 3);
            #pragma unroll
            for (int co = 0; co < CO; ++co) {
                if (r < 3)
                    #pragma unroll
                    for (int j = 0; j < 4; ++j)
                        acc[co][0][j] = dot4(sw[j], wv[r][co], acc[co][0][j]);
                if (r >= 1)
                    #pragma unroll
                    for (int j = 0; j < 4; ++j)
                        acc[co][1][j] = dot4(sw[j], wv[r - 1][co], acc[co][1][j]);
            }
        }
    }

    #pragma unroll
    for (int co = 0; co < CO; ++co) {
        const int c = cg * CO + co;
        #pragma unroll
        for (int rr = 0; rr < 2; ++rr) {
            const int y = py + rr;
            if (y >= Wo) continue;
            if (OUT_NHWC) {
                int8_t* o = outp + (((size_t)n * Wo + y) * Wo + px) * cout + c;
                #pragma unroll
                for (int j = 0; j < 4; ++j)
                    if (px + j < Wo) {
                        int a = acc[co][rr][j];
                        a = a > 1 ? 1 : (a < -1 ? -1 : a);
                        o[(size_t)j * cout] = (int8_t)a;
                    }
            } else {
                int8_t* o = outp + ((size_t)n * cout + c) * ((size_t)Wo * WSo)
                          + (size_t)y * WSo + px;
                if (px + 4 <= Wo) {
                    uint32_t u = 0;
                    #pragma unroll
                    for (int j = 0; j < 4; ++j) {
                        int a = acc[co][rr][j];
                        a = a > 1 ? 1 : (a < -1 ? -1 : a);
                        u |= ((uint32_t)(uint8_t)(int8_t)a) << (8 * j);
                    }
                    *(uint32_t*)o = u;
                } else {
                    #pragma unroll
                    for (int j = 0; j < 4; ++j)
                        if (px + j < Wo) {
                            int a = acc[co][rr][j];
                            a = a > 1 ? 1 : (a < -1 ? -1 : a);
                            o[j] = (int8_t)a;
                        }
                }
            }
        }
    }
}

// ---------------- L3..L6: implicit-GEMM MFMA conv, NHWC int8, B double-buffered.
// v_mfma_i32_16x16x64_i8: A lane l: m=l&15, k=(l>>4)*16+j ; B: n=l&15, same k ;
// D: n=l&15, m=(l>>4)*4+reg. K packs TP=64/CIN taps of cin channels.
// Block = 4 waves = 4 consecutive output rows; each wave: 16*MTILES couts x
// full row in 16-pixel fragments (nf = ceil(Wo/16) = 8 for all four layers;
// last fragment overlaps — duplicate writes of identical values are benign).
template <int CIN, int COUT, int MTILES, bool FOUT>
__global__ __launch_bounds__(256) void conv_mfma(
    const int8_t* __restrict__ in, const float* __restrict__ w,
    void* __restrict__ outp, int Wi, int Wo)
{
    constexpr int TP  = 64 / CIN;            // taps per MFMA
    constexpr int NMF = (9 + TP - 1) / TP;   // MFMAs per K-accumulation
    __shared__ int8_t aw[MTILES * NMF * 1024];

    const int t  = threadIdx.x;
    const int cg = blockIdx.x;
    const int n  = blockIdx.z;

    // Build sign-packed A fragments in LDS (layout = exact lane order).
    for (int idx = t; idx < MTILES * NMF * 1024; idx += 256) {
        const int mt  = idx / (NMF * 1024);
        const int rem = idx % (NMF * 1024);
        const int f   = rem >> 10;
        const int l   = (rem >> 4) & 63;
        const int j   = rem & 15;
        const int m   = l & 15;
        const int g   = l >> 4;
        const int k   = g * 16 + j;
        const int tap = f * TP + k / CIN;
        const int ci  = k % CIN;
        const int co  = cg * (16 * MTILES) + mt * 16 + m;
        int8_t s = 0;
        if (tap < 9 && co < COUT) {
            float v = w[((size_t)co * CIN + ci) * 9 + tap];
            s = (v > 0.f) ? (int8_t)1 : ((v < 0.f) ? (int8_t)(-1) : (int8_t)0);
        }
        aw[idx] = s;
    }
    __syncthreads();

    const int wv = t >> 6;
    const int l  = t & 63;
    const int g  = l >> 4;
    const int npix = l & 15;
    const int y = blockIdx.y * 4 + wv;
    if (y >= Wo) return;

    i32x4 a[MTILES][NMF];
    #pragma unroll
    for (int mt = 0; mt < MTILES; ++mt)
        #pragma unroll
        for (int f = 0; f < NMF; ++f)
            a[mt][f] = *(const i32x4*)&aw[((mt * NMF + f) << 10) + (l << 4)];

    // Per-lane tap byte-offsets into the NHWC input.
    int boff[NMF];
    const int gdiv = (g * 16) / CIN;
    const int coff = (g * 16) % CIN;
    #pragma unroll
    for (int f = 0; f < NMF; ++f) {
        int tap = f * TP + gdiv;
        if (tap > 8) tap = 8;  // A is zero there; any in-bounds address works
        boff[f] = ((tap / 3) * Wi + (tap % 3)) * CIN + coff;
    }

    const int8_t* rowlane = in + (size_t)n * Wi * Wi * CIN
                          + (size_t)y * Wi * CIN + npix * CIN;
    const int nf = (Wo + 15) >> 4;

    auto ldB = [&](int i, i32x4* bv) {
        int x0 = i << 4;
        if (x0 > Wo - 16) x0 = Wo - 16;
        const int8_t* p = rowlane + (size_t)x0 * CIN;
        #pragma unroll
        for (int f = 0; f < NMF; ++f)
            bv[f] = *(const i32x4*)(p + boff[f]);
    };

    auto comp = [&](int i, const i32x4* bv) {
        int x0 = i << 4;
        if (x0 > Wo - 16) x0 = Wo - 16;
        i32x4 acc[MTILES];
        #pragma unroll
        for (int mt = 0; mt < MTILES; ++mt) {
            acc[mt] = (i32x4){0, 0, 0, 0};
            #pragma unroll
            for (int f = 0; f < NMF; ++f)
                acc[mt] = __builtin_amdgcn_mfma_i32_16x16x64_i8(a[mt][f], bv[f], acc[mt], 0, 0, 0);
        }
        if (!FOUT) {
            uint8_t* orow = (uint8_t*)outp + ((size_t)n * Wo + y) * (size_t)Wo * COUT
                          + (size_t)(x0 + npix) * COUT + cg * (16 * MTILES) + (g << 2);
            #pragma unroll
            for (int mt = 0; mt < MTILES; ++mt) {
                uint32_t u = 0;
                #pragma unroll
                for (int r = 0; r < 4; ++r) {
                    int v = acc[mt][r];
                    v = v > 1 ? 1 : (v < -1 ? -1 : v);
                    u |= ((uint32_t)(uint8_t)(int8_t)v) << (8 * r);
                }
                *(uint32_t*)(orow + mt * 16) = u;
            }
        } else {
            float* fo = (float*)outp;
            #pragma unroll
            for (int r = 0; r < 4; ++r) {
                const int m = g * 4 + r;
                if (m < COUT) {
                    int v = acc[0][r];
                    v = v > 1 ? 1 : (v < -1 ? -1 : v);
                    fo[((size_t)(n * COUT + m) * Wo + y) * Wo + x0 + npix] = (float)v;
                }
            }
        }
    };

    // Register double-buffer: loads for fragment i+1 are in flight while
    // fragment i's MFMAs run (compiler emits partial vmcnt waits).
    i32x4 b0[NMF], b1[NMF];
    ldB(0, b0);
    for (int i = 0; i < nf; i += 2) {
        const bool has1 = (i + 1) < nf;
        ldB(has1 ? i + 1 : i, b1);
        comp(i, b0);
        if (i + 2 < nf) ldB(i + 2, b0);
        if (has1) comp(i + 1, b1);
    }
}

extern "C" void kernel_launch(void* const* d_in, const int* in_sizes, int n_in,
                              void* d_out, int out_size, void* d_ws, size_t ws_size,
                              hipStream_t stream) {
    const float* x  = (const float*)d_in[0];
    const float* w0 = (const float*)d_in[1];
    const float* w1 = (const float*)d_in[2];
    const float* w2 = (const float*)d_in[3];
    const float* w3 = (const float*)d_in[4];
    const float* w4 = (const float*)d_in[5];
    const float* w5 = (const float*)d_in[6];
    const float* w6 = (const float*)d_in[7];

    int8_t* A = (int8_t*)d_ws;
    int8_t* B = A + 58491136;

    // L0: (64,3,256,256) fp32 -> signs NCHW (64,4,127,s128)
    conv0_pool_sign<<<16129, 256, 0, stream>>>(x, w0, A);

    auto gy = [](int Wo) { return ((Wo + 63) / 64) * ((Wo + 31) / 32); };

    // L1: 4->8, NCHW s128 -> NCHW s128, 127 -> 125
    conv_dot<4, 4, false><<<dim3(2, gy(125), 64), 256, 0, stream>>>(A, w1, B, 8, 127, 128, 125, 128);
    // L2: 8->16, NCHW s128 -> NHWC, 125 -> 123
    conv_dot<8, 4, true ><<<dim3(4, gy(123), 64), 256, 0, stream>>>(B, w2, A, 16, 125, 128, 123, 0);

    // L3: 16->32, NHWC, 123 -> 121.  TP=4, NMF=3, MTILES=2 -> 32 couts/block
    conv_mfma<16, 32, 2, false><<<dim3(1, (121 + 3) / 4, 64), 256, 0, stream>>>(A, w3, B, 123, 121);
    // L4: 32->64, NHWC, 121 -> 119.  TP=2, NMF=5, MTILES=4 -> all 64 couts/block
    conv_mfma<32, 64, 4, false><<<dim3(1, (119 + 3) / 4, 64), 256, 0, stream>>>(B, w4, A, 121, 119);
    // L5: 64->32, NHWC, 119 -> 117.  TP=1, NMF=9, MTILES=2
    conv_mfma<64, 32, 2, false><<<dim3(1, (117 + 3) / 4, 64), 256, 0, stream>>>(A, w5, B, 119, 117);
    // L6: 32->2, NHWC -> float NCHW d_out, 117 -> 115.  MTILES=1
    conv_mfma<32, 2, 1, true ><<<dim3(1, (115 + 3) / 4, 64), 256, 0, stream>>>(B, w6, d_out, 117, 115);
}

// Round 5
// 442.854 us; speedup vs baseline: 1.0242x; 1.0242x over previous
//
#include <hip/hip_runtime.h>
#include <stdint.h>

// Ternary CNN, 7 layers. L0: fp64-exact conv+pool+sign (NCHW). L1-L2: sdot4
// kernels (NCHW in; L2 emits NHWC). L3-L6: implicit-GEMM int8 MFMA in NHWC
// with the block's 6 input rows staged in LDS as CIN/16 planes of 16B
// pixel-records (pixel stride 16B -> 2 lanes/bank -> conflict-free
// ds_read_b128 B-fragments). Register double-buffer across 16-pixel
// fragments. Global reads per block = unique 6 rows only.
//
// Workspace ping-pong:
//  A @ 0        : L0 out NCHW (64,4,127,s128) 4.2MB ; L2 out NHWC (64,123,123,16) 15.5MB ;
//                 L4 out NHWC (64,119,119,64) 58.0MB
//  B @ 58491136 : L1 out NCHW (64,8,125,s128) 8.2MB ; L3 out NHWC (64,121,121,32) 30.0MB ;
//                 L5 out NHWC (64,117,117,32) 28.1MB

#define DEVINL __device__ __forceinline__
typedef int i32x4 __attribute__((ext_vector_type(4)));

DEVINL uint32_t alignb(uint32_t hi, uint32_t lo, int k) {
#if __has_builtin(__builtin_amdgcn_alignbyte)
    return __builtin_amdgcn_alignbyte(hi, lo, (uint32_t)k);
#else
    return (uint32_t)(((((uint64_t)hi) << 32) | (uint64_t)lo) >> (8 * k));
#endif
}

DEVINL int dot4(uint32_t a, uint32_t b, int c) {
#if __has_builtin(__builtin_amdgcn_sdot4)
    return __builtin_amdgcn_sdot4((int)a, (int)b, c, false);
#else
    #pragma unroll
    for (int i = 0; i < 4; ++i)
        c += (int)(int8_t)(a >> (8 * i)) * (int)(int8_t)(b >> (8 * i));
    return c;
#endif
}

// ---------------- Layer 0: conv(raw fp32, sign(w)) -> maxpool2 -> sign -> int8 NCHW s128
__global__ __launch_bounds__(256) void conv0_pool_sign(
    const float* __restrict__ x, const float* __restrict__ w,
    int8_t* __restrict__ out)
{
    __shared__ float ws[108];
    const int t = threadIdx.x;
    if (t < 108) {
        float v = w[t];
        ws[t] = (v > 0.f) ? 1.f : ((v < 0.f) ? -1.f : 0.f);
    }
    __syncthreads();
    const int idx = blockIdx.x * 256 + t;   // 64*4*127*127 = 16129*256
    const int px = idx % 127;
    const int py = (idx / 127) % 127;
    const int co = (idx / (127 * 127)) % 4;
    const int n  = idx / (127 * 127 * 4);

    double a00 = 0.0, a01 = 0.0, a10 = 0.0, a11 = 0.0;
    const float* wsc = &ws[co * 27];
    for (int ci = 0; ci < 3; ++ci) {
        float patch[4][4];
        const float* xp = x + (((size_t)n * 3 + ci) * 256 + 2 * py) * 256 + 2 * px;
        #pragma unroll
        for (int r = 0; r < 4; ++r) {
            const float2* q = (const float2*)(xp + r * 256);
            float2 p01 = q[0], p23 = q[1];
            patch[r][0] = p01.x; patch[r][1] = p01.y;
            patch[r][2] = p23.x; patch[r][3] = p23.y;
        }
        #pragma unroll
        for (int ky = 0; ky < 3; ++ky)
            #pragma unroll
            for (int kx = 0; kx < 3; ++kx) {
                const double wv = (double)wsc[ci * 9 + ky * 3 + kx];
                a00 += (double)patch[ky][kx]         * wv;
                a01 += (double)patch[ky][kx + 1]     * wv;
                a10 += (double)patch[ky + 1][kx]     * wv;
                a11 += (double)patch[ky + 1][kx + 1] * wv;
            }
    }
    const double m = fmax(fmax(a00, a01), fmax(a10, a11));
    const size_t o = (((size_t)n * 4 + co) * 127 + py) * 128 + px;
    out[o] = (m > 0.0) ? (int8_t)1 : ((m < 0.0) ? (int8_t)(-1) : (int8_t)0);
}

// ---------------- L1/L2: ternary conv via sdot4 (NCHW in). OUT_NHWC: byte-store NHWC.
template <int CIN, int CO, bool OUT_NHWC>
__global__ __launch_bounds__(256) void conv_dot(
    const int8_t* __restrict__ in, const float* __restrict__ w,
    int8_t* __restrict__ outp, int cout, int W, int WS, int Wo, int WSo)
{
    __shared__ uint32_t pw[CIN * 3 * CO];
    const int t  = threadIdx.x;
    const int cg = blockIdx.x;
    const int n  = blockIdx.z;
    for (int i = t; i < CIN * 3 * CO; i += 256) {
        const int co = i % CO;
        const int r  = i / CO;
        const int ky = r % 3;
        const int ci = r / 3;
        const float* wp = w + (((size_t)(cg * CO + co) * CIN + ci) * 9 + ky * 3);
        uint32_t u = 0;
        #pragma unroll
        for (int k = 0; k < 3; ++k) {
            float v = wp[k];
            int s = (v > 0.f) ? 1 : ((v < 0.f) ? -1 : 0);
            u |= ((uint32_t)(uint8_t)(int8_t)s) << (8 * k);
        }
        pw[i] = u;
    }
    __syncthreads();

    const int tiles_x = (Wo + 63) >> 6;
    const int bx = blockIdx.y % tiles_x;
    const int by = blockIdx.y / tiles_x;
    const int px = bx * 64 + (t & 15) * 4;
    const int py = by * 32 + (t >> 4) * 2;
    if (px >= Wo || py >= Wo) return;

    const size_t ch = (size_t)W * WS;
    const int8_t* p0 = in + (size_t)n * CIN * ch + (size_t)py * WS + px;
    const int r3off = (py + 3 < W) ? 3 * WS : 0;

    int acc[CO][2][4];
    #pragma unroll
    for (int co = 0; co < CO; ++co)
        #pragma unroll
        for (int rr = 0; rr < 2; ++rr)
            #pragma unroll
            for (int j = 0; j < 4; ++j) acc[co][rr][j] = 0;

    #pragma unroll 2
    for (int ci = 0; ci < CIN; ++ci) {
        const int8_t* p = p0 + (size_t)ci * ch;
        uint32_t da[4], db[4];
        {
            const uint32_t* q0 = (const uint32_t*)p;
            const uint32_t* q1 = (const uint32_t*)(p + WS);
            const uint32_t* q2 = (const uint32_t*)(p + 2 * WS);
            const uint32_t* q3 = (const uint32_t*)(p + r3off);
            da[0] = q0[0]; db[0] = q0[1];
            da[1] = q1[0]; db[1] = q1[1];
            da[2] = q2[0]; db[2] = q2[1];
            da[3] = q3[0]; db[3] = q3[1];
        }
        uint32_t wv[3][CO];
        #pragma unroll
        for (int ky = 0; ky < 3; ++ky)
            #pragma unroll
            for (int co = 0; co < CO; ++co)
                wv[ky][co] = pw[(ci * 3 + ky) * CO + co];

        #pragma unroll
        for (int r = 0; r < 4; ++r) {
            uint32_t sw[4];
            sw[0] = da[r];
            sw[1] = alignb(db[r], da[r], 1);
            sw[2] = alignb(db[r], da[r], 2);
            sw[3] = alignb(db[r], da[r], 3);
            #pragma unroll
            for (int co = 0; co < CO; ++co) {
                if (r < 3)
                    #pragma unroll
                    for (int j = 0; j < 4; ++j)
                        acc[co][0][j] = dot4(sw[j], wv[r][co], acc[co][0][j]);
                if (r >= 1)
                    #pragma unroll
                    for (int j = 0; j < 4; ++j)
                        acc[co][1][j] = dot4(sw[j], wv[r - 1][co], acc[co][1][j]);
            }
        }
    }

    #pragma unroll
    for (int co = 0; co < CO; ++co) {
        const int c = cg * CO + co;
        #pragma unroll
        for (int rr = 0; rr < 2; ++rr) {
            const int y = py + rr;
            if (y >= Wo) continue;
            if (OUT_NHWC) {
                int8_t* o = outp + (((size_t)n * Wo + y) * Wo + px) * cout + c;
                #pragma unroll
                for (int j = 0; j < 4; ++j)
                    if (px + j < Wo) {
                        int a = acc[co][rr][j];
                        a = a > 1 ? 1 : (a < -1 ? -1 : a);
                        o[(size_t)j * cout] = (int8_t)a;
                    }
            } else {
                int8_t* o = outp + ((size_t)n * cout + c) * ((size_t)Wo * WSo)
                          + (size_t)y * WSo + px;
                if (px + 4 <= Wo) {
                    uint32_t u = 0;
                    #pragma unroll
                    for (int j = 0; j < 4; ++j) {
                        int a = acc[co][rr][j];
                        a = a > 1 ? 1 : (a < -1 ? -1 : a);
                        u |= ((uint32_t)(uint8_t)(int8_t)a) << (8 * j);
                    }
                    *(uint32_t*)o = u;
                } else {
                    #pragma unroll
                    for (int j = 0; j < 4; ++j)
                        if (px + j < Wo) {
                            int a = acc[co][rr][j];
                            a = a > 1 ? 1 : (a < -1 ? -1 : a);
                            o[j] = (int8_t)a;
                        }
                }
            }
        }
    }
}

// ---------------- L3..L6: implicit-GEMM MFMA conv, NHWC int8, LDS-staged input.
// v_mfma_i32_16x16x64_i8: A lane l: m=l&15, k=(l>>4)*16+j ; B: n=l&15, same k ;
// D: n=l&15, m=(l>>4)*4+reg. K packs TP=64/CIN taps of cin channels.
// Block = 4 waves = 4 consecutive output rows. Phase 1: sign-packed A
// fragments via LDS -> registers. Phase 2: stage 6 input rows into LDS as
// NP=CIN/16 planes of 16B pixel-records (conflict-free b128 reads).
// Phase 3: per 16-pixel fragment, NMF ds_read_b128 + MTILES*NMF MFMAs,
// double-buffered.
template <int CIN, int COUT, int MTILES, int WI, bool FOUT>
__global__ __launch_bounds__(256) void conv_mfma(
    const int8_t* __restrict__ in, const float* __restrict__ w,
    void* __restrict__ outp, int Wo)
{
    constexpr int TP  = 64 / CIN;            // taps per MFMA
    constexpr int NMF = (9 + TP - 1) / TP;   // MFMAs per K-accumulation
    constexpr int NP  = CIN / 16;            // 16B planes
    constexpr int PS  = 6 * WI * 16;         // plane size, bytes
    constexpr int ABYTES = MTILES * NMF * 1024;
    constexpr int TBYTES = NP * PS;
    constexpr int LBYTES = ABYTES > TBYTES ? ABYTES : TBYTES;
    __shared__ __align__(16) int8_t lds[LBYTES];

    const int t  = threadIdx.x;
    const int cg = blockIdx.x;
    const int n  = blockIdx.z;
    const int y0 = blockIdx.y * 4;

    // --- Phase 1: build sign-packed A fragments in LDS, read to registers.
    for (int idx = t; idx < ABYTES; idx += 256) {
        const int mt  = idx / (NMF * 1024);
        const int rem = idx % (NMF * 1024);
        const int f   = rem >> 10;
        const int l   = (rem >> 4) & 63;
        const int j   = rem & 15;
        const int m   = l & 15;
        const int g   = l >> 4;
        const int k   = g * 16 + j;
        const int tap = f * TP + k / CIN;
        const int ci  = k % CIN;
        const int co  = cg * (16 * MTILES) + mt * 16 + m;
        int8_t s = 0;
        if (tap < 9 && co < COUT) {
            float v = w[((size_t)co * CIN + ci) * 9 + tap];
            s = (v > 0.f) ? (int8_t)1 : ((v < 0.f) ? (int8_t)(-1) : (int8_t)0);
        }
        lds[idx] = s;
    }
    __syncthreads();

    const int wv = t >> 6;
    const int l  = t & 63;
    const int g  = l >> 4;
    const int npix = l & 15;

    i32x4 a[MTILES][NMF];
    #pragma unroll
    for (int mt = 0; mt < MTILES; ++mt)
        #pragma unroll
        for (int f = 0; f < NMF; ++f)
            a[mt][f] = *(const i32x4*)&lds[((mt * NMF + f) << 10) + (l << 4)];
    __syncthreads();   // A region about to be overwritten by the tile

    // --- Phase 2: stage 6 input rows (planar 16B records).
    {
        const int8_t* nin = in + (size_t)n * WI * WI * CIN;
        for (int idx = t; idx < NP * 6 * WI; idx += 256) {
            const int plane = idx / (6 * WI);
            const int rp    = idx % (6 * WI);
            const int row   = rp / WI;
            const int col   = rp % WI;
            int grow = y0 + row; if (grow > WI - 1) grow = WI - 1;  // staged, unused
            i32x4 v = *(const i32x4*)(nin + ((size_t)grow * WI + col) * CIN + plane * 16);
            *(i32x4*)&lds[plane * PS + rp * 16] = v;
        }
    }
    __syncthreads();

    const int y = y0 + wv;
    if (y >= Wo) return;   // only after all barriers

    // Per-lane LDS byte-offsets per MFMA fragment.
    const int gdiv  = (g * 16) / CIN;
    const int plane = ((g * 16) % CIN) / 16;
    int loff[NMF];
    #pragma unroll
    for (int f = 0; f < NMF; ++f) {
        int tap = f * TP + gdiv;
        if (tap > 8) tap = 8;  // A is zero there; any valid address works
        loff[f] = plane * PS + (((wv + tap / 3) * WI + (tap % 3) + npix) << 4);
    }

    const int nf = (Wo + 15) >> 4;

    auto ldB = [&](int i, i32x4* bv) {
        int x0 = i << 4;
        if (x0 > Wo - 16) x0 = Wo - 16;
        #pragma unroll
        for (int f = 0; f < NMF; ++f)
            bv[f] = *(const i32x4*)&lds[loff[f] + (x0 << 4)];
    };

    auto comp = [&](int i, const i32x4* bv) {
        int x0 = i << 4;
        if (x0 > Wo - 16) x0 = Wo - 16;
        i32x4 acc[MTILES];
        #pragma unroll
        for (int mt = 0; mt < MTILES; ++mt) {
            acc[mt] = (i32x4){0, 0, 0, 0};
            #pragma unroll
            for (int f = 0; f < NMF; ++f)
                acc[mt] = __builtin_amdgcn_mfma_i32_16x16x64_i8(a[mt][f], bv[f], acc[mt], 0, 0, 0);
        }
        if (!FOUT) {
            uint8_t* orow = (uint8_t*)outp + ((size_t)n * Wo + y) * (size_t)Wo * COUT
                          + (size_t)(x0 + npix) * COUT + cg * (16 * MTILES) + (g << 2);
            #pragma unroll
            for (int mt = 0; mt < MTILES; ++mt) {
                uint32_t u = 0;
                #pragma unroll
                for (int r = 0; r < 4; ++r) {
                    int v = acc[mt][r];
                    v = v > 1 ? 1 : (v < -1 ? -1 : v);
                    u |= ((uint32_t)(uint8_t)(int8_t)v) << (8 * r);
                }
                *(uint32_t*)(orow + mt * 16) = u;
            }
        } else {
            float* fo = (float*)outp;
            #pragma unroll
            for (int r = 0; r < 4; ++r) {
                const int m = g * 4 + r;
                if (m < COUT) {
                    int v = acc[0][r];
                    v = v > 1 ? 1 : (v < -1 ? -1 : v);
                    fo[((size_t)(n * COUT + m) * Wo + y) * Wo + x0 + npix] = (float)v;
                }
            }
        }
    };

    // Register double-buffer across fragments (partial lgkmcnt waits).
    i32x4 b0[NMF], b1[NMF];
    ldB(0, b0);
    for (int i = 0; i < nf; i += 2) {
        const bool has1 = (i + 1) < nf;
        ldB(has1 ? i + 1 : i, b1);
        comp(i, b0);
        if (i + 2 < nf) ldB(i + 2, b0);
        if (has1) comp(i + 1, b1);
    }
}

extern "C" void kernel_launch(void* const* d_in, const int* in_sizes, int n_in,
                              void* d_out, int out_size, void* d_ws, size_t ws_size,
                              hipStream_t stream) {
    const float* x  = (const float*)d_in[0];
    const float* w0 = (const float*)d_in[1];
    const float* w1 = (const float*)d_in[2];
    const float* w2 = (const float*)d_in[3];
    const float* w3 = (const float*)d_in[4];
    const float* w4 = (const float*)d_in[5];
    const float* w5 = (const float*)d_in[6];
    const float* w6 = (const float*)d_in[7];

    int8_t* A = (int8_t*)d_ws;
    int8_t* B = A + 58491136;

    // L0: (64,3,256,256) fp32 -> signs NCHW (64,4,127,s128)
    conv0_pool_sign<<<16129, 256, 0, stream>>>(x, w0, A);

    auto gy = [](int Wo) { return ((Wo + 63) / 64) * ((Wo + 31) / 32); };

    // L1: 4->8, NCHW s128 -> NCHW s128, 127 -> 125
    conv_dot<4, 4, false><<<dim3(2, gy(125), 64), 256, 0, stream>>>(A, w1, B, 8, 127, 128, 125, 128);
    // L2: 8->16, NCHW s128 -> NHWC, 125 -> 123
    conv_dot<8, 4, true ><<<dim3(4, gy(123), 64), 256, 0, stream>>>(B, w2, A, 16, 125, 128, 123, 0);

    // L3: 16->32, NHWC, 123 -> 121.  TP=4, NMF=3, MTILES=2
    conv_mfma<16, 32, 2, 123, false><<<dim3(1, 31, 64), 256, 0, stream>>>(A, w3, B, 121);
    // L4: 32->64, NHWC, 121 -> 119.  TP=2, NMF=5, MTILES=2, grid.x=2
    conv_mfma<32, 64, 2, 121, false><<<dim3(2, 30, 64), 256, 0, stream>>>(B, w4, A, 119);
    // L5: 64->32, NHWC, 119 -> 117.  TP=1, NMF=9, MTILES=2
    conv_mfma<64, 32, 2, 119, false><<<dim3(1, 30, 64), 256, 0, stream>>>(A, w5, B, 117);
    // L6: 32->2, NHWC -> float NCHW d_out, 117 -> 115.  MTILES=1
    conv_mfma<32, 2, 1, 117, true ><<<dim3(1, 29, 64), 256, 0, stream>>>(B, w6, d_out, 115);
}

// Round 6
// 326.349 us; speedup vs baseline: 1.3899x; 1.3570x over previous
//
#include <hip/hip_runtime.h>
#include <stdint.h>

// Ternary CNN, 7 layers. L0: fp64-exact conv+pool+sign (NCHW). L1-L2: sdot4
// kernels (NCHW in; L2 emits NHWC). L3-L6: implicit-GEMM int8 MFMA in NHWC.
// Round 6: A-fragments are PREPACKED ONCE by a tiny kernel (was: every block
// re-decoded 18KB of weights with divides + scattered loads = dominant fixed
// cost at 3 blocks/CU residency). conv_mfma blocks now: coalesced dwordx4
// A-load, pixel-major staging of 6 rows x 66 cols into LDS planes, ONE
// barrier, 4 fragments of ds_read_b128 + MFMA.
//
// Workspace:
//  A  @ 0        : L0 out NCHW (64,4,127,s128); L2 out NHWC (64,123,123,16); L4 out NHWC
//  B  @ 58491136 : L1 out NCHW (64,8,125,s128); L3 out NHWC (64,121,121,32); L5 out NHWC
//  pA @ 88475904 : packed sign A-fragments, 50176 B (L3@0, L4@6144, L5@26624, L6@45056)

#define DEVINL __device__ __forceinline__
typedef int i32x4 __attribute__((ext_vector_type(4)));

DEVINL uint32_t alignb(uint32_t hi, uint32_t lo, int k) {
#if __has_builtin(__builtin_amdgcn_alignbyte)
    return __builtin_amdgcn_alignbyte(hi, lo, (uint32_t)k);
#else
    return (uint32_t)(((((uint64_t)hi) << 32) | (uint64_t)lo) >> (8 * k));
#endif
}

DEVINL int dot4(uint32_t a, uint32_t b, int c) {
#if __has_builtin(__builtin_amdgcn_sdot4)
    return __builtin_amdgcn_sdot4((int)a, (int)b, c, false);
#else
    #pragma unroll
    for (int i = 0; i < 4; ++i)
        c += (int)(int8_t)(a >> (8 * i)) * (int)(int8_t)(b >> (8 * i));
    return c;
#endif
}

// ---------------- Layer 0: conv(raw fp32, sign(w)) -> maxpool2 -> sign -> int8 NCHW s128
__global__ __launch_bounds__(256) void conv0_pool_sign(
    const float* __restrict__ x, const float* __restrict__ w,
    int8_t* __restrict__ out)
{
    __shared__ float ws[108];
    const int t = threadIdx.x;
    if (t < 108) {
        float v = w[t];
        ws[t] = (v > 0.f) ? 1.f : ((v < 0.f) ? -1.f : 0.f);
    }
    __syncthreads();
    const int idx = blockIdx.x * 256 + t;   // 64*4*127*127 = 16129*256
    const int px = idx % 127;
    const int py = (idx / 127) % 127;
    const int co = (idx / (127 * 127)) % 4;
    const int n  = idx / (127 * 127 * 4);

    double a00 = 0.0, a01 = 0.0, a10 = 0.0, a11 = 0.0;
    const float* wsc = &ws[co * 27];
    for (int ci = 0; ci < 3; ++ci) {
        float patch[4][4];
        const float* xp = x + (((size_t)n * 3 + ci) * 256 + 2 * py) * 256 + 2 * px;
        #pragma unroll
        for (int r = 0; r < 4; ++r) {
            const float2* q = (const float2*)(xp + r * 256);
            float2 p01 = q[0], p23 = q[1];
            patch[r][0] = p01.x; patch[r][1] = p01.y;
            patch[r][2] = p23.x; patch[r][3] = p23.y;
        }
        #pragma unroll
        for (int ky = 0; ky < 3; ++ky)
            #pragma unroll
            for (int kx = 0; kx < 3; ++kx) {
                const double wv = (double)wsc[ci * 9 + ky * 3 + kx];
                a00 += (double)patch[ky][kx]         * wv;
                a01 += (double)patch[ky][kx + 1]     * wv;
                a10 += (double)patch[ky + 1][kx]     * wv;
                a11 += (double)patch[ky + 1][kx + 1] * wv;
            }
    }
    const double m = fmax(fmax(a00, a01), fmax(a10, a11));
    const size_t o = (((size_t)n * 4 + co) * 127 + py) * 128 + px;
    out[o] = (m > 0.0) ? (int8_t)1 : ((m < 0.0) ? (int8_t)(-1) : (int8_t)0);
}

// ---------------- L1/L2: ternary conv via sdot4 (NCHW in). OUT_NHWC: byte-store NHWC.
template <int CIN, int CO, bool OUT_NHWC>
__global__ __launch_bounds__(256) void conv_dot(
    const int8_t* __restrict__ in, const float* __restrict__ w,
    int8_t* __restrict__ outp, int cout, int W, int WS, int Wo, int WSo)
{
    __shared__ uint32_t pw[CIN * 3 * CO];
    const int t  = threadIdx.x;
    const int cg = blockIdx.x;
    const int n  = blockIdx.z;
    for (int i = t; i < CIN * 3 * CO; i += 256) {
        const int co = i % CO;
        const int r  = i / CO;
        const int ky = r % 3;
        const int ci = r / 3;
        const float* wp = w + (((size_t)(cg * CO + co) * CIN + ci) * 9 + ky * 3);
        uint32_t u = 0;
        #pragma unroll
        for (int k = 0; k < 3; ++k) {
            float v = wp[k];
            int s = (v > 0.f) ? 1 : ((v < 0.f) ? -1 : 0);
            u |= ((uint32_t)(uint8_t)(int8_t)s) << (8 * k);
        }
        pw[i] = u;
    }
    __syncthreads();

    const int tiles_x = (Wo + 63) >> 6;
    const int bx = blockIdx.y % tiles_x;
    const int by = blockIdx.y / tiles_x;
    const int px = bx * 64 + (t & 15) * 4;
    const int py = by * 32 + (t >> 4) * 2;
    if (px >= Wo || py >= Wo) return;

    const size_t ch = (size_t)W * WS;
    const int8_t* p0 = in + (size_t)n * CIN * ch + (size_t)py * WS + px;
    const int r3off = (py + 3 < W) ? 3 * WS : 0;

    int acc[CO][2][4];
    #pragma unroll
    for (int co = 0; co < CO; ++co)
        #pragma unroll
        for (int rr = 0; rr < 2; ++rr)
            #pragma unroll
            for (int j = 0; j < 4; ++j) acc[co][rr][j] = 0;

    #pragma unroll 2
    for (int ci = 0; ci < CIN; ++ci) {
        const int8_t* p = p0 + (size_t)ci * ch;
        uint32_t da[4], db[4];
        {
            const uint32_t* q0 = (const uint32_t*)p;
            const uint32_t* q1 = (const uint32_t*)(p + WS);
            const uint32_t* q2 = (const uint32_t*)(p + 2 * WS);
            const uint32_t* q3 = (const uint32_t*)(p + r3off);
            da[0] = q0[0]; db[0] = q0[1];
            da[1] = q1[0]; db[1] = q1[1];
            da[2] = q2[0]; db[2] = q2[1];
            da[3] = q3[0]; db[3] = q3[1];
        }
        uint32_t wv[3][CO];
        #pragma unroll
        for (int ky = 0; ky < 3; ++ky)
            #pragma unroll
            for (int co = 0; co < CO; ++co)
                wv[ky][co] = pw[(ci * 3 + ky) * CO + co];

        #pragma unroll
        for (int r = 0; r < 4; ++r) {
            uint32_t sw[4];
            sw[0] = da[r];
            sw[1] = alignb(db[r], da[r], 1);
            sw[2] = alignb(db[r], da[r], 2);
            sw[3] = alignb(db[r], da[r], 3);
            #pragma unroll
            for (int co = 0; co < CO; ++co) {
                if (r < 3)
                    #pragma unroll
                    for (int j = 0; j < 4; ++j)
                        acc[co][0][j] = dot4(sw[j], wv[r][co], acc[co][0][j]);
                if (r >= 1)
                    #pragma unroll
                    for (int j = 0; j < 4; ++j)
                        acc[co][1][j] = dot4(sw[j], wv[r - 1][co], acc[co][1][j]);
            }
        }
    }

    #pragma unroll
    for (int co = 0; co < CO; ++co) {
        const int c = cg * CO + co;
        #pragma unroll
        for (int rr = 0; rr < 2; ++rr) {
            const int y = py + rr;
            if (y >= Wo) continue;
            if (OUT_NHWC) {
                int8_t* o = outp + (((size_t)n * Wo + y) * Wo + px) * cout + c;
                #pragma unroll
                for (int j = 0; j < 4; ++j)
                    if (px + j < Wo) {
                        int a = acc[co][rr][j];
                        a = a > 1 ? 1 : (a < -1 ? -1 : a);
                        o[(size_t)j * cout] = (int8_t)a;
                    }
            } else {
                int8_t* o = outp + ((size_t)n * cout + c) * ((size_t)Wo * WSo)
                          + (size_t)y * WSo + px;
                if (px + 4 <= Wo) {
                    uint32_t u = 0;
                    #pragma unroll
                    for (int j = 0; j < 4; ++j) {
                        int a = acc[co][rr][j];
                        a = a > 1 ? 1 : (a < -1 ? -1 : a);
                        u |= ((uint32_t)(uint8_t)(int8_t)a) << (8 * j);
                    }
                    *(uint32_t*)o = u;
                } else {
                    #pragma unroll
                    for (int j = 0; j < 4; ++j)
                        if (px + j < Wo) {
                            int a = acc[co][rr][j];
                            a = a > 1 ? 1 : (a < -1 ? -1 : a);
                            o[j] = (int8_t)a;
                        }
                }
            }
        }
    }
}

// ---------------- Prepack sign A-fragments for L3..L6 (runs once, 50176 B).
// Byte layout per layer segment: cg-major, then mt, f, lane l, j — exactly the
// order conv_mfma's lanes consume via dwordx4.
__global__ __launch_bounds__(256) void prepack_w(
    const float* __restrict__ w3, const float* __restrict__ w4,
    const float* __restrict__ w5, const float* __restrict__ w6,
    int8_t* __restrict__ pA)
{
    const int idx = blockIdx.x * 256 + threadIdx.x;
    const float* w; int CIN, COUT, MTILES, NMF, off;
    if      (idx < 6144)  { w = w3; CIN = 16; COUT = 32; MTILES = 2; NMF = 3; off = 0; }
    else if (idx < 26624) { w = w4; CIN = 32; COUT = 64; MTILES = 2; NMF = 5; off = 6144; }
    else if (idx < 45056) { w = w5; CIN = 64; COUT = 32; MTILES = 2; NMF = 9; off = 26624; }
    else if (idx < 50176) { w = w6; CIN = 32; COUT = 2;  MTILES = 1; NMF = 5; off = 45056; }
    else return;
    const int TP = 64 / CIN;
    const int s   = idx - off;
    const int per = MTILES * NMF * 1024;
    const int cg  = s / per;
    const int rem = s % per;
    const int mt  = rem / (NMF * 1024);
    const int r2  = rem % (NMF * 1024);
    const int f   = r2 >> 10;
    const int l   = (r2 >> 4) & 63;
    const int j   = r2 & 15;
    const int m   = l & 15;
    const int g   = l >> 4;
    const int k   = g * 16 + j;
    const int tap = f * TP + k / CIN;
    const int ci  = k % CIN;
    const int co  = cg * (16 * MTILES) + mt * 16 + m;
    int8_t v = 0;
    if (tap < 9 && co < COUT) {
        float x = w[((size_t)co * CIN + ci) * 9 + tap];
        v = (x > 0.f) ? (int8_t)1 : ((x < 0.f) ? (int8_t)(-1) : (int8_t)0);
    }
    pA[idx] = v;
}

// ---------------- L3..L6: implicit-GEMM MFMA conv, NHWC int8, prepacked A.
// v_mfma_i32_16x16x64_i8: A lane l: m=l&15, k=(l>>4)*16+j ; B: n=l&15, same k ;
// D: n=l&15, m=(l>>4)*4+reg. K packs TP=64/CIN taps of cin channels.
// Block = 4 waves = 4 rows x 4 fragments (half the width); grid.y = ny*2.
// Stage 6 rows x 66 cols as NP=CIN/16 planes of 16B records (pixel-major
// global loads: full 64B pixel records, streaming). One barrier.
template <int CIN, int COUT, int MTILES, int WI, bool FOUT>
__global__ __launch_bounds__(256) void conv_mfma(
    const int8_t* __restrict__ in, const int8_t* __restrict__ packA,
    void* __restrict__ outp, int Wo)
{
    constexpr int TP  = 64 / CIN;
    constexpr int NMF = (9 + TP - 1) / TP;
    constexpr int NP  = CIN / 16;
    constexpr int CB  = 66;                 // staged cols per x-half
    __shared__ __align__(16) int8_t lds[NP * 6 * CB * 16];

    const int t  = threadIdx.x;
    const int cg = blockIdx.x;
    const int n  = blockIdx.z;
    const int by = blockIdx.y >> 1;
    const int bx = blockIdx.y & 1;
    const int y0 = by * 4;
    const int f0 = bx * 4;                  // first of 4 fragments
    const int cbase = f0 * 16;
    const int ncols = (WI - cbase < CB) ? (WI - cbase) : CB;
    const int npx   = 6 * ncols;

    // ---- issue staging loads: pixel-major, full 64B records
    const int8_t* nin = in + (size_t)n * WI * WI * CIN;
    i32x4 st[2][NP];
    #pragma unroll
    for (int u = 0; u < 2; ++u) {
        int p  = t + u * 256;
        int pp = p < npx ? p : npx - 1;
        int row  = pp / ncols;
        int col  = cbase + pp % ncols;
        int grow = y0 + row; if (grow > WI - 1) grow = WI - 1;
        const int8_t* src = nin + ((size_t)grow * WI + col) * CIN;
        #pragma unroll
        for (int pl = 0; pl < NP; ++pl)
            st[u][pl] = *(const i32x4*)(src + pl * 16);
    }

    // ---- A fragments from prepacked global (coalesced, L2-hot)
    const int l = t & 63, wv = t >> 6, g = l >> 4, npix = l & 15;
    i32x4 a[MTILES][NMF];
    {
        const int8_t* ap = packA + (size_t)cg * MTILES * NMF * 1024 + l * 16;
        #pragma unroll
        for (int mt = 0; mt < MTILES; ++mt)
            #pragma unroll
            for (int f = 0; f < NMF; ++f)
                a[mt][f] = *(const i32x4*)(ap + (mt * NMF + f) * 1024);
    }

    // ---- write staged pixels to LDS planes
    #pragma unroll
    for (int u = 0; u < 2; ++u) {
        int p = t + u * 256;
        if (p < npx) {
            int row = p / ncols, colrel = p % ncols;
            #pragma unroll
            for (int pl = 0; pl < NP; ++pl)
                *(i32x4*)&lds[(size_t)(pl * 6 * CB + row * CB + colrel) * 16] = st[u][pl];
        }
    }
    __syncthreads();

    const int y = y0 + wv;
    if (y >= Wo) return;

    // per-lane LDS offsets per fragment-MFMA
    const int gdiv  = (g * 16) / CIN;
    const int plane = ((g * 16) % CIN) / 16;
    int loff[NMF];
    #pragma unroll
    for (int f = 0; f < NMF; ++f) {
        int tap = f * TP + gdiv;
        if (tap > 8) tap = 8;               // A is zero there; any valid addr
        loff[f] = (plane * 6 * CB + (wv + tap / 3) * CB + (tap % 3) + npix) << 4;
    }

    #pragma unroll
    for (int i = 0; i < 4; ++i) {
        int x0 = (f0 + i) * 16;
        if (x0 > Wo - 16) x0 = Wo - 16;
        const int xrel = x0 - cbase;

        i32x4 bv[NMF];
        #pragma unroll
        for (int f = 0; f < NMF; ++f)
            bv[f] = *(const i32x4*)&lds[loff[f] + (xrel << 4)];

        i32x4 acc[MTILES];
        #pragma unroll
        for (int mt = 0; mt < MTILES; ++mt) {
            acc[mt] = (i32x4){0, 0, 0, 0};
            #pragma unroll
            for (int f = 0; f < NMF; ++f)
                acc[mt] = __builtin_amdgcn_mfma_i32_16x16x64_i8(a[mt][f], bv[f], acc[mt], 0, 0, 0);
        }

        if (!FOUT) {
            uint8_t* orow = (uint8_t*)outp + ((size_t)n * Wo + y) * (size_t)Wo * COUT
                          + (size_t)(x0 + npix) * COUT + cg * (16 * MTILES) + (g << 2);
            #pragma unroll
            for (int mt = 0; mt < MTILES; ++mt) {
                uint32_t u = 0;
                #pragma unroll
                for (int r = 0; r < 4; ++r) {
                    int v = acc[mt][r];
                    v = v > 1 ? 1 : (v < -1 ? -1 : v);
                    u |= ((uint32_t)(uint8_t)(int8_t)v) << (8 * r);
                }
                *(uint32_t*)(orow + mt * 16) = u;
            }
        } else {
            float* fo = (float*)outp;
            #pragma unroll
            for (int r = 0; r < 4; ++r) {
                const int m = g * 4 + r;
                if (m < COUT) {
                    int v = acc[0][r];
                    v = v > 1 ? 1 : (v < -1 ? -1 : v);
                    fo[((size_t)(n * COUT + m) * Wo + y) * Wo + x0 + npix] = (float)v;
                }
            }
        }
    }
}

extern "C" void kernel_launch(void* const* d_in, const int* in_sizes, int n_in,
                              void* d_out, int out_size, void* d_ws, size_t ws_size,
                              hipStream_t stream) {
    const float* x  = (const float*)d_in[0];
    const float* w0 = (const float*)d_in[1];
    const float* w1 = (const float*)d_in[2];
    const float* w2 = (const float*)d_in[3];
    const float* w3 = (const float*)d_in[4];
    const float* w4 = (const float*)d_in[5];
    const float* w5 = (const float*)d_in[6];
    const float* w6 = (const float*)d_in[7];

    int8_t* A  = (int8_t*)d_ws;
    int8_t* B  = A + 58491136;
    int8_t* pA = B + 29984768;   // 50176 B of packed A-fragments

    // Prepack weights for the MFMA layers (once per call, ~2 us).
    prepack_w<<<196, 256, 0, stream>>>(w3, w4, w5, w6, pA);

    // L0: (64,3,256,256) fp32 -> signs NCHW (64,4,127,s128)
    conv0_pool_sign<<<16129, 256, 0, stream>>>(x, w0, A);

    auto gy = [](int Wo) { return ((Wo + 63) / 64) * ((Wo + 31) / 32); };

    // L1: 4->8, NCHW s128 -> NCHW s128, 127 -> 125
    conv_dot<4, 4, false><<<dim3(2, gy(125), 64), 256, 0, stream>>>(A, w1, B, 8, 127, 128, 125, 128);
    // L2: 8->16, NCHW s128 -> NHWC, 125 -> 123
    conv_dot<8, 4, true ><<<dim3(4, gy(123), 64), 256, 0, stream>>>(B, w2, A, 16, 125, 128, 123, 0);

    // L3: 16->32, NHWC, 123 -> 121.  ny=31
    conv_mfma<16, 32, 2, 123, false><<<dim3(1, 31 * 2, 64), 256, 0, stream>>>(A, pA + 0, B, 121);
    // L4: 32->64, NHWC, 121 -> 119.  ny=30, 2 cout-groups
    conv_mfma<32, 64, 2, 121, false><<<dim3(2, 30 * 2, 64), 256, 0, stream>>>(B, pA + 6144, A, 119);
    // L5: 64->32, NHWC, 119 -> 117.  ny=30
    conv_mfma<64, 32, 2, 119, false><<<dim3(1, 30 * 2, 64), 256, 0, stream>>>(A, pA + 26624, B, 117);
    // L6: 32->2, NHWC -> float NCHW d_out, 117 -> 115.  ny=29
    conv_mfma<32, 2, 1, 117, true ><<<dim3(1, 29 * 2, 64), 256, 0, stream>>>(B, pA + 45056, d_out, 115);
}

// Round 7
// 240.281 us; speedup vs baseline: 1.8877x; 1.3582x over previous
//
#include <hip/hip_runtime.h>
#include <stdint.h>

// Ternary CNN, 7 layers, all-NHWC pipeline.
// L0: fp64-exact conv+pool+sign -> NHWC C=4 (one thread = one pixel, all 4
//     couts, dword store; per-output accumulation order identical to r1-r6).
// L1: NHWC4 -> NHWC8 via dot4(pixel_record, w_record) per tap (channels
//     reduced inside dot4). Dense 8B/pixel stores.
// L2: NHWC8 -> NHWC16, same scheme with 2 dwords/pixel. Dense 16B stores.
// L3-L6: implicit-GEMM int8 MFMA (prepacked A-fragments, LDS-staged rows).
// Round 7 fix: r6's top dispatch was L2's byte-scatter NHWC store (62MB HBM
// writes for 15.5MB useful = 4x RMW amplification). Now every thread writes
// full pixel records -> no partial-line RMW.
//
// Workspace:
//  A  @ 0        : L0 out NHWC4 (64,127,127,4) 4.1MB ; L2 out NHWC16 15.5MB ; L4 out NHWC64 58.0MB
//  B  @ 58491136 : L1 out NHWC8 (64,125,125,8) 8.0MB ; L3 out NHWC32 30.0MB ; L5 out NHWC32 28.1MB
//  pA @ 88475904 : packed sign A-fragments, 50176 B (L3@0, L4@6144, L5@26624, L6@45056)

#define DEVINL __device__ __forceinline__
typedef int i32x4 __attribute__((ext_vector_type(4)));

DEVINL int dot4(uint32_t a, uint32_t b, int c) {
#if __has_builtin(__builtin_amdgcn_sdot4)
    return __builtin_amdgcn_sdot4((int)a, (int)b, c, false);
#else
    #pragma unroll
    for (int i = 0; i < 4; ++i)
        c += (int)(int8_t)(a >> (8 * i)) * (int)(int8_t)(b >> (8 * i));
    return c;
#endif
}

DEVINL uint32_t clampb(int v) {           // clamp to [-1,1], return low byte
    v = v > 1 ? 1 : (v < -1 ? -1 : v);
    return (uint32_t)(uint8_t)(int8_t)v;
}

// ---------------- Layer 0: conv(raw fp32, sign(w)) -> maxpool2 -> sign -> NHWC4
__global__ __launch_bounds__(256) void conv0_pool_sign(
    const float* __restrict__ x, const float* __restrict__ w,
    uint32_t* __restrict__ out)
{
    __shared__ float ws[108];
    const int t = threadIdx.x;
    if (t < 108) {
        float v = w[t];
        ws[t] = (v > 0.f) ? 1.f : ((v < 0.f) ? -1.f : 0.f);
    }
    __syncthreads();
    const int idx = blockIdx.x * 256 + t;
    if (idx >= 64 * 127 * 127) return;
    const int px = idx % 127;
    const int py = (idx / 127) % 127;
    const int n  = idx / (127 * 127);

    double acc[4][4];   // [co][pos]
    #pragma unroll
    for (int co = 0; co < 4; ++co)
        #pragma unroll
        for (int p = 0; p < 4; ++p) acc[co][p] = 0.0;

    for (int ci = 0; ci < 3; ++ci) {
        float patch[4][4];
        const float* xp = x + (((size_t)n * 3 + ci) * 256 + 2 * py) * 256 + 2 * px;
        #pragma unroll
        for (int r = 0; r < 4; ++r) {
            const float2* q = (const float2*)(xp + r * 256);
            float2 p01 = q[0], p23 = q[1];
            patch[r][0] = p01.x; patch[r][1] = p01.y;
            patch[r][2] = p23.x; patch[r][3] = p23.y;
        }
        #pragma unroll
        for (int co = 0; co < 4; ++co) {
            const float* wsc = &ws[co * 27 + ci * 9];
            #pragma unroll
            for (int ky = 0; ky < 3; ++ky)
                #pragma unroll
                for (int kx = 0; kx < 3; ++kx) {
                    const double wv = (double)wsc[ky * 3 + kx];
                    acc[co][0] += (double)patch[ky][kx]         * wv;
                    acc[co][1] += (double)patch[ky][kx + 1]     * wv;
                    acc[co][2] += (double)patch[ky + 1][kx]     * wv;
                    acc[co][3] += (double)patch[ky + 1][kx + 1] * wv;
                }
        }
    }
    uint32_t u = 0;
    #pragma unroll
    for (int co = 0; co < 4; ++co) {
        const double m = fmax(fmax(acc[co][0], acc[co][1]), fmax(acc[co][2], acc[co][3]));
        const uint32_t s = (m > 0.0) ? 1u : ((m < 0.0) ? 0xFFu : 0u);
        u |= s << (8 * co);
    }
    out[idx] = u;   // idx == (n*127+py)*127+px
}

// ---------------- L1: NHWC4 (127x127) -> NHWC8 (125x125)
__global__ __launch_bounds__(256) void conv_l1(
    const uint32_t* __restrict__ in, const float* __restrict__ w,
    uint2* __restrict__ out)
{
    __shared__ uint32_t pw[72];   // [co*9+tap], 4 ci per dword
    const int t = threadIdx.x;
    if (t < 72) {
        const int co = t / 9, tap = t % 9;
        uint32_t u = 0;
        #pragma unroll
        for (int ci = 0; ci < 4; ++ci) {
            float v = w[(co * 4 + ci) * 9 + tap];
            uint32_t s = (v > 0.f) ? 1u : ((v < 0.f) ? 0xFFu : 0u);
            u |= s << (8 * ci);
        }
        pw[t] = u;
    }
    __syncthreads();

    const int idx = blockIdx.x * 256 + t;   // 64*125*32 = 256000 exact
    const int xg  = idx & 31;
    const int rest = idx >> 5;
    const int py  = rest % 125;
    const int n   = rest / 125;
    int px0 = xg * 4; if (px0 > 121) px0 = 121;

    const uint32_t* base = in + ((size_t)(n * 127 + py) * 127 + px0);
    uint32_t d[3][6];
    #pragma unroll
    for (int r = 0; r < 3; ++r)
        #pragma unroll
        for (int c = 0; c < 6; ++c)
            d[r][c] = base[r * 127 + c];

    int acc[4][8];
    #pragma unroll
    for (int j = 0; j < 4; ++j)
        #pragma unroll
        for (int co = 0; co < 8; ++co) acc[j][co] = 0;

    #pragma unroll
    for (int ky = 0; ky < 3; ++ky)
        #pragma unroll
        for (int kx = 0; kx < 3; ++kx) {
            const int tap = ky * 3 + kx;
            #pragma unroll
            for (int co = 0; co < 8; ++co) {
                const uint32_t wv = pw[co * 9 + tap];
                #pragma unroll
                for (int j = 0; j < 4; ++j)
                    acc[j][co] = dot4(d[ky][j + kx], wv, acc[j][co]);
            }
        }

    uint2* orow = out + ((size_t)(n * 125 + py) * 125 + px0);
    #pragma unroll
    for (int j = 0; j < 4; ++j) {
        uint32_t u0 = 0, u1 = 0;
        #pragma unroll
        for (int co = 0; co < 4; ++co) u0 |= clampb(acc[j][co]) << (8 * co);
        #pragma unroll
        for (int co = 0; co < 4; ++co) u1 |= clampb(acc[j][co + 4]) << (8 * co);
        orow[j] = make_uint2(u0, u1);
    }
}

// ---------------- L2: NHWC8 (125x125) -> NHWC16 (123x123)
__global__ __launch_bounds__(256) void conv_l2(
    const uint32_t* __restrict__ in, const float* __restrict__ w,
    i32x4* __restrict__ out)
{
    __shared__ uint32_t pw[288];   // [(co*9+tap)*2 + half]
    const int t = threadIdx.x;
    for (int i = t; i < 288; i += 256) {
        const int co = i / 18, r = i % 18, tap = r / 2, half = r % 2;
        uint32_t u = 0;
        #pragma unroll
        for (int ci = 0; ci < 4; ++ci) {
            float v = w[(co * 8 + half * 4 + ci) * 9 + tap];
            uint32_t s = (v > 0.f) ? 1u : ((v < 0.f) ? 0xFFu : 0u);
            u |= s << (8 * ci);
        }
        pw[i] = u;
    }
    __syncthreads();

    const int idx = blockIdx.x * 256 + t;
    if (idx >= 64 * 123 * 31) return;
    const int xg   = idx % 31;
    const int rest = idx / 31;
    const int py   = rest % 123;
    const int n    = rest / 123;
    int px0 = xg * 4; if (px0 > 119) px0 = 119;

    const uint32_t* base = in + ((size_t)(n * 125 + py) * 125 + px0) * 2;
    uint32_t d[3][6][2];
    #pragma unroll
    for (int r = 0; r < 3; ++r)
        #pragma unroll
        for (int c = 0; c < 6; ++c) {
            d[r][c][0] = base[(r * 125 + c) * 2];
            d[r][c][1] = base[(r * 125 + c) * 2 + 1];
        }

    int acc[4][16];
    #pragma unroll
    for (int j = 0; j < 4; ++j)
        #pragma unroll
        for (int co = 0; co < 16; ++co) acc[j][co] = 0;

    #pragma unroll
    for (int ky = 0; ky < 3; ++ky)
        #pragma unroll
        for (int kx = 0; kx < 3; ++kx) {
            const int tap = ky * 3 + kx;
            #pragma unroll
            for (int co = 0; co < 16; ++co) {
                const uint32_t w0 = pw[(co * 9 + tap) * 2];
                const uint32_t w1 = pw[(co * 9 + tap) * 2 + 1];
                #pragma unroll
                for (int j = 0; j < 4; ++j)
                    acc[j][co] = dot4(d[ky][j + kx][1], w1,
                                 dot4(d[ky][j + kx][0], w0, acc[j][co]));
            }
        }

    i32x4* orow = out + ((size_t)(n * 123 + py) * 123 + px0);
    #pragma unroll
    for (int j = 0; j < 4; ++j) {
        uint32_t u[4];
        #pragma unroll
        for (int q = 0; q < 4; ++q) {
            u[q] = 0;
            #pragma unroll
            for (int b = 0; b < 4; ++b)
                u[q] |= clampb(acc[j][q * 4 + b]) << (8 * b);
        }
        orow[j] = (i32x4){(int)u[0], (int)u[1], (int)u[2], (int)u[3]};
    }
}

// ---------------- Prepack sign A-fragments for L3..L6 (runs once, 50176 B).
__global__ __launch_bounds__(256) void prepack_w(
    const float* __restrict__ w3, const float* __restrict__ w4,
    const float* __restrict__ w5, const float* __restrict__ w6,
    int8_t* __restrict__ pA)
{
    const int idx = blockIdx.x * 256 + threadIdx.x;
    const float* w; int CIN, COUT, MTILES, NMF, off;
    if      (idx < 6144)  { w = w3; CIN = 16; COUT = 32; MTILES = 2; NMF = 3; off = 0; }
    else if (idx < 26624) { w = w4; CIN = 32; COUT = 64; MTILES = 2; NMF = 5; off = 6144; }
    else if (idx < 45056) { w = w5; CIN = 64; COUT = 32; MTILES = 2; NMF = 9; off = 26624; }
    else if (idx < 50176) { w = w6; CIN = 32; COUT = 2;  MTILES = 1; NMF = 5; off = 45056; }
    else return;
    const int TP = 64 / CIN;
    const int s   = idx - off;
    const int per = MTILES * NMF * 1024;
    const int cg  = s / per;
    const int rem = s % per;
    const int mt  = rem / (NMF * 1024);
    const int r2  = rem % (NMF * 1024);
    const int f   = r2 >> 10;
    const int l   = (r2 >> 4) & 63;
    const int j   = r2 & 15;
    const int m   = l & 15;
    const int g   = l >> 4;
    const int k   = g * 16 + j;
    const int tap = f * TP + k / CIN;
    const int ci  = k % CIN;
    const int co  = cg * (16 * MTILES) + mt * 16 + m;
    int8_t v = 0;
    if (tap < 9 && co < COUT) {
        float x = w[((size_t)co * CIN + ci) * 9 + tap];
        v = (x > 0.f) ? (int8_t)1 : ((x < 0.f) ? (int8_t)(-1) : (int8_t)0);
    }
    pA[idx] = v;
}

// ---------------- L3..L6: implicit-GEMM MFMA conv, NHWC int8, prepacked A.
template <int CIN, int COUT, int MTILES, int WI, bool FOUT>
__global__ __launch_bounds__(256) void conv_mfma(
    const int8_t* __restrict__ in, const int8_t* __restrict__ packA,
    void* __restrict__ outp, int Wo)
{
    constexpr int TP  = 64 / CIN;
    constexpr int NMF = (9 + TP - 1) / TP;
    constexpr int NP  = CIN / 16;
    constexpr int CB  = 66;
    __shared__ __align__(16) int8_t lds[NP * 6 * CB * 16];

    const int t  = threadIdx.x;
    const int cg = blockIdx.x;
    const int n  = blockIdx.z;
    const int by = blockIdx.y >> 1;
    const int bx = blockIdx.y & 1;
    const int y0 = by * 4;
    const int f0 = bx * 4;
    const int cbase = f0 * 16;
    const int ncols = (WI - cbase < CB) ? (WI - cbase) : CB;
    const int npx   = 6 * ncols;

    const int8_t* nin = in + (size_t)n * WI * WI * CIN;
    i32x4 st[2][NP];
    #pragma unroll
    for (int u = 0; u < 2; ++u) {
        int p  = t + u * 256;
        int pp = p < npx ? p : npx - 1;
        int row  = pp / ncols;
        int col  = cbase + pp % ncols;
        int grow = y0 + row; if (grow > WI - 1) grow = WI - 1;
        const int8_t* src = nin + ((size_t)grow * WI + col) * CIN;
        #pragma unroll
        for (int pl = 0; pl < NP; ++pl)
            st[u][pl] = *(const i32x4*)(src + pl * 16);
    }

    const int l = t & 63, wv = t >> 6, g = l >> 4, npix = l & 15;
    i32x4 a[MTILES][NMF];
    {
        const int8_t* ap = packA + (size_t)cg * MTILES * NMF * 1024 + l * 16;
        #pragma unroll
        for (int mt = 0; mt < MTILES; ++mt)
            #pragma unroll
            for (int f = 0; f < NMF; ++f)
                a[mt][f] = *(const i32x4*)(ap + (mt * NMF + f) * 1024);
    }

    #pragma unroll
    for (int u = 0; u < 2; ++u) {
        int p = t + u * 256;
        if (p < npx) {
            int row = p / ncols, colrel = p % ncols;
            #pragma unroll
            for (int pl = 0; pl < NP; ++pl)
                *(i32x4*)&lds[(size_t)(pl * 6 * CB + row * CB + colrel) * 16] = st[u][pl];
        }
    }
    __syncthreads();

    const int y = y0 + wv;
    if (y >= Wo) return;

    const int gdiv  = (g * 16) / CIN;
    const int plane = ((g * 16) % CIN) / 16;
    int loff[NMF];
    #pragma unroll
    for (int f = 0; f < NMF; ++f) {
        int tap = f * TP + gdiv;
        if (tap > 8) tap = 8;
        loff[f] = (plane * 6 * CB + (wv + tap / 3) * CB + (tap % 3) + npix) << 4;
    }

    #pragma unroll
    for (int i = 0; i < 4; ++i) {
        int x0 = (f0 + i) * 16;
        if (x0 > Wo - 16) x0 = Wo - 16;
        const int xrel = x0 - cbase;

        i32x4 bv[NMF];
        #pragma unroll
        for (int f = 0; f < NMF; ++f)
            bv[f] = *(const i32x4*)&lds[loff[f] + (xrel << 4)];

        i32x4 acc[MTILES];
        #pragma unroll
        for (int mt = 0; mt < MTILES; ++mt) {
            acc[mt] = (i32x4){0, 0, 0, 0};
            #pragma unroll
            for (int f = 0; f < NMF; ++f)
                acc[mt] = __builtin_amdgcn_mfma_i32_16x16x64_i8(a[mt][f], bv[f], acc[mt], 0, 0, 0);
        }

        if (!FOUT) {
            uint8_t* orow = (uint8_t*)outp + ((size_t)n * Wo + y) * (size_t)Wo * COUT
                          + (size_t)(x0 + npix) * COUT + cg * (16 * MTILES) + (g << 2);
            #pragma unroll
            for (int mt = 0; mt < MTILES; ++mt) {
                uint32_t u = 0;
                #pragma unroll
                for (int r = 0; r < 4; ++r)
                    u |= clampb(acc[mt][r]) << (8 * r);
                *(uint32_t*)(orow + mt * 16) = u;
            }
        } else {
            float* fo = (float*)outp;
            #pragma unroll
            for (int r = 0; r < 4; ++r) {
                const int m = g * 4 + r;
                if (m < COUT) {
                    int v = acc[0][r];
                    v = v > 1 ? 1 : (v < -1 ? -1 : v);
                    fo[((size_t)(n * COUT + m) * Wo + y) * Wo + x0 + npix] = (float)v;
                }
            }
        }
    }
}

extern "C" void kernel_launch(void* const* d_in, const int* in_sizes, int n_in,
                              void* d_out, int out_size, void* d_ws, size_t ws_size,
                              hipStream_t stream) {
    const float* x  = (const float*)d_in[0];
    const float* w0 = (const float*)d_in[1];
    const float* w1 = (const float*)d_in[2];
    const float* w2 = (const float*)d_in[3];
    const float* w3 = (const float*)d_in[4];
    const float* w4 = (const float*)d_in[5];
    const float* w5 = (const float*)d_in[6];
    const float* w6 = (const float*)d_in[7];

    int8_t* A  = (int8_t*)d_ws;
    int8_t* B  = A + 58491136;
    int8_t* pA = B + 29984768;

    prepack_w<<<196, 256, 0, stream>>>(w3, w4, w5, w6, pA);

    // L0: (64,3,256,256) fp32 -> NHWC4 (64,127,127,4)
    conv0_pool_sign<<<4033, 256, 0, stream>>>(x, w0, (uint32_t*)A);
    // L1: NHWC4 -> NHWC8 (64,125,125,8)
    conv_l1<<<1000, 256, 0, stream>>>((const uint32_t*)A, w1, (uint2*)B);
    // L2: NHWC8 -> NHWC16 (64,123,123,16)
    conv_l2<<<954, 256, 0, stream>>>((const uint32_t*)B, w2, (i32x4*)A);

    // L3: 16->32, 123 -> 121
    conv_mfma<16, 32, 2, 123, false><<<dim3(1, 31 * 2, 64), 256, 0, stream>>>(A, pA + 0, B, 121);
    // L4: 32->64, 121 -> 119
    conv_mfma<32, 64, 2, 121, false><<<dim3(2, 30 * 2, 64), 256, 0, stream>>>(B, pA + 6144, A, 119);
    // L5: 64->32, 119 -> 117
    conv_mfma<64, 32, 2, 119, false><<<dim3(1, 30 * 2, 64), 256, 0, stream>>>(A, pA + 26624, B, 117);
    // L6: 32->2, 117 -> 115, float NCHW out
    conv_mfma<32, 2, 1, 117, true ><<<dim3(1, 29 * 2, 64), 256, 0, stream>>>(B, pA + 45056, d_out, 115);
}